// Round 5
// baseline (27.177 us; speedup 1.0000x reference)
//
#include <hip/hip_runtime.h>

#define B_TOTAL 4096
#define D 32
#define H 256
#define SPB 8            // samples per block (M=8 of the MFMA's 16 rows used)
#define HPW 64           // hidden units per wave (4 waves x 64 = 256)

static constexpr float EPS = 0.1f;

typedef __attribute__((ext_vector_type(8))) short short8v;   // 8 x bf16
typedef __attribute__((ext_vector_type(4))) float f32x4;

__device__ __forceinline__ unsigned short bf16rne(float f) {
  unsigned u = __float_as_uint(f);
  u += 0x7FFFu + ((u >> 16) & 1u);           // round-to-nearest-even
  return (unsigned short)(u >> 16);
}
__device__ __forceinline__ float fromb(unsigned short h) {
  return __uint_as_float(((unsigned)h) << 16);
}
__device__ __forceinline__ void split_bf16(float f, unsigned short& hi, unsigned short& lo) {
  hi = bf16rne(f);
  lo = bf16rne(f - fromb(hi));
}

#define MFMA16(A, Bf, C) __builtin_amdgcn_mfma_f32_16x16x32_bf16((A), (Bf), (C), 0, 0, 0)

__global__ __launch_bounds__(256, 2) void ma_flow_kernel(
    const float* __restrict__ x_in, const float* __restrict__ logp_in,
    const float* __restrict__ w1, const float* __restrict__ b1,
    const float* __restrict__ w2, float* __restrict__ out)
{
  // a-transpose buffer (wave-local): packed (lo<<16)|hi bf16 per h. row stride 68 dw (272B, 16B-aligned)
  __shared__ __align__(16) unsigned aBuf[4][16][68];
  // per-wave partial g (+lap in col 32), double-buffered by stage parity. row stride 36 dw (144B)
  __shared__ __align__(16) float partG[2][4][16][36];

  const int tid = threadIdx.x;
  const int l  = tid & 63;
  const int wv = tid >> 6;       // wave id = h-slice
  const int lr = l & 15;         // MFMA m/n lane index; also owned sample
  const int lg = l >> 4;         // MFMA k-group; also owned dim-octet
  const int hbase = wv * HPW;

  // ---------------- weight fragments (registers, hi/lo bf16 split) -------------
  // z-pass: B[k=d][n=h]. lane: k = lg*8+j, n = tau*16+lr
  short8v Bzh[4], Bzl[4];
  float b1v[4], w2v[4], w2cv[4];
#pragma unroll
  for (int tau = 0; tau < 4; ++tau) {
    const int h = hbase + tau * 16 + lr;
    float cpart = 0.0f;
    short8v hi, lo;
#pragma unroll
    for (int j = 0; j < 8; ++j) {
      float w = w1[(lg * 8 + j) * H + h];
      cpart = fmaf(w, w, cpart);
      unsigned short hb, lb; split_bf16(w, hb, lb);
      hi[j] = (short)hb; lo[j] = (short)lb;
    }
    Bzh[tau] = hi; Bzl[tau] = lo;
    cpart += __shfl_xor(cpart, 16);            // sum the 4 k-groups -> c_h
    cpart += __shfl_xor(cpart, 32);
    b1v[tau] = b1[h];
    float w2x = w2[h];
    w2v[tau] = w2x;
    w2cv[tau] = w2x * cpart;                   // w2[h] * sum_d w1[d,h]^2
  }
  // g-pass: B[k=h][n=d] (w1^T). lane: k = kp*32+lg*8+j, n = nu*16+lr
  short8v Bgh[2][2], Bgl[2][2];
#pragma unroll
  for (int nu = 0; nu < 2; ++nu)
#pragma unroll
    for (int kp = 0; kp < 2; ++kp) {
      const int d = nu * 16 + lr;
      const float* p = w1 + d * H + (hbase + kp * 32 + lg * 8);
      float4 v0 = *reinterpret_cast<const float4*>(p);
      float4 v1 = *reinterpret_cast<const float4*>(p + 4);
      float wv8[8] = {v0.x, v0.y, v0.z, v0.w, v1.x, v1.y, v1.z, v1.w};
      short8v hi, lo;
#pragma unroll
      for (int j = 0; j < 8; ++j) {
        unsigned short hb, lb; split_bf16(wv8[j], hb, lb);
        hi[j] = (short)hb; lo[j] = (short)lb;
      }
      Bgh[nu][kp] = hi; Bgl[nu][kp] = lo;
    }

  // ---------------- register-resident state ------------------------------------
  // lane (lr,lg) owns sample lr (if lr<SPB), dims lg*8..lg*8+7
  float x0r[8], accr[8], xcr[8], lp = 0.0f;
#pragma unroll
  for (int j = 0; j < 8; ++j) { x0r[j] = 0.0f; accr[j] = 0.0f; xcr[j] = 0.0f; }
  if (lr < SPB) {
    const float* xp = x_in + (blockIdx.x * SPB + lr) * D + lg * 8;
    float4 v0 = *reinterpret_cast<const float4*>(xp);
    float4 v1 = *reinterpret_cast<const float4*>(xp + 4);
    x0r[0] = v0.x; x0r[1] = v0.y; x0r[2] = v0.z; x0r[3] = v0.w;
    x0r[4] = v1.x; x0r[5] = v1.y; x0r[6] = v1.z; x0r[7] = v1.w;
#pragma unroll
    for (int j = 0; j < 8; ++j) xcr[j] = x0r[j];
    lp = logp_in[blockIdx.x * SPB + lr];
  }

  // ---------------- 8 RK4 stage evaluations, ONE barrier each ------------------
  int p = 0;
#pragma unroll 1
  for (int stage = 0; stage < 8; ++stage) {
    const int st = stage & 3;
    const float wa = (st == 0 || st == 3) ? (EPS / 6.0f) : (EPS / 3.0f);
    const float wc = (st == 2) ? EPS : (EPS * 0.5f);

    // -- phase 1: xc regs -> A-frags, z-MFMAs, sigmoid, packed aBuf write ------
    short8v ahi, alo;
#pragma unroll
    for (int j = 0; j < 8; ++j) {
      unsigned short hb, lb; split_bf16(xcr[j], hb, lb);
      ahi[j] = (short)hb; alo[j] = (short)lb;
    }

    float lapp[4] = {0.0f, 0.0f, 0.0f, 0.0f};
#pragma unroll
    for (int tau = 0; tau < 4; ++tau) {
      f32x4 z = {b1v[tau], b1v[tau], b1v[tau], b1v[tau]};
      z = MFMA16(ahi, Bzh[tau], z);
      z = MFMA16(alo, Bzh[tau], z);
      z = MFMA16(ahi, Bzl[tau], z);
#pragma unroll
      for (int r = 0; r < 4; ++r) {
        float e = __expf(-z[r]);
        float s = __builtin_amdgcn_rcpf(1.0f + e);           // sigmoid
        lapp[r] = fmaf(s * (1.0f - s), w2cv[tau], lapp[r]);  // laplacian partial
        float a = s * w2v[tau];
        unsigned short ah, al; split_bf16(a, ah, al);
        aBuf[wv][lg * 4 + r][tau * 16 + lr] = ((unsigned)al << 16) | (unsigned)ah;
      }
    }
    // wave-local fence: aBuf write->read within this wave (DS in-order + drain)
    asm volatile("s_waitcnt lgkmcnt(0)" ::: "memory");
    __builtin_amdgcn_sched_barrier(0);

    // -- phase 2: aBuf -> A-frags (hi+lo), g-MFMAs, partG writes ---------------
    short8v aH[2], aL[2];
#pragma unroll
    for (int c = 0; c < 2; ++c) {
      const unsigned* ap = &aBuf[wv][lr][c * 32 + lg * 8];
      uint4 q0 = *reinterpret_cast<const uint4*>(ap);
      uint4 q1 = *reinterpret_cast<const uint4*>(ap + 4);
      unsigned uu[8] = {q0.x, q0.y, q0.z, q0.w, q1.x, q1.y, q1.z, q1.w};
      short8v h_, l_;
#pragma unroll
      for (int j = 0; j < 8; ++j) {
        h_[j] = (short)(uu[j] & 0xFFFFu);
        l_[j] = (short)(uu[j] >> 16);
      }
      aH[c] = h_; aL[c] = l_;
    }
#pragma unroll
    for (int nu = 0; nu < 2; ++nu) {
      f32x4 g = {0.0f, 0.0f, 0.0f, 0.0f};
      g = MFMA16(aH[0], Bgh[nu][0], g);
      g = MFMA16(aL[0], Bgh[nu][0], g);
      g = MFMA16(aH[0], Bgl[nu][0], g);
      g = MFMA16(aH[1], Bgh[nu][1], g);
      g = MFMA16(aL[1], Bgh[nu][1], g);
      g = MFMA16(aH[1], Bgl[nu][1], g);
#pragma unroll
      for (int r = 0; r < 4; ++r)
        partG[p][wv][lg * 4 + r][nu * 16 + lr] = g[r];
    }
    // laplacian: reduce over the wave's 16 h-columns, deposit in col 32
#pragma unroll
    for (int m = 1; m < 16; m <<= 1)
#pragma unroll
      for (int r = 0; r < 4; ++r) lapp[r] += __shfl_xor(lapp[r], m);
    if (lr == 0) {
#pragma unroll
      for (int r = 0; r < 4; ++r) partG[p][wv][lg * 4 + r][32] = lapp[r];
    }
    __syncthreads();   // the stage's single barrier

    // -- phase 3: cross-wave reduce straight into register state ---------------
    f32x4 ga = {0.0f, 0.0f, 0.0f, 0.0f}, gb = {0.0f, 0.0f, 0.0f, 0.0f};
    float lapt = 0.0f;
#pragma unroll
    for (int w = 0; w < 4; ++w) {
      const float* q = &partG[p][w][lr][lg * 8];
      ga += *reinterpret_cast<const f32x4*>(q);
      gb += *reinterpret_cast<const f32x4*>(q + 4);
      lapt += partG[p][w][lr][32];
    }
    float gv[8] = {ga.x, ga.y, ga.z, ga.w, gb.x, gb.y, gb.z, gb.w};
    lp = fmaf(-wa, lapt, lp);
#pragma unroll
    for (int j = 0; j < 8; ++j) {
      accr[j] = fmaf(wa, gv[j], accr[j]);
      if (st < 3) {
        xcr[j] = fmaf(wc, gv[j], x0r[j]);
      } else {
        x0r[j] += accr[j];
        xcr[j] = x0r[j];
        accr[j] = 0.0f;
      }
    }
    p ^= 1;            // partG double-buffer: WAR covered by next stage's barrier
  }

  // ---------------- output ------------------------------------------------------
  if (lr < SPB) {
    float* op = out + (blockIdx.x * SPB + lr) * D + lg * 8;
    float4 v0, v1;
    v0.x = x0r[0]; v0.y = x0r[1]; v0.z = x0r[2]; v0.w = x0r[3];
    v1.x = x0r[4]; v1.y = x0r[5]; v1.z = x0r[6]; v1.w = x0r[7];
    *reinterpret_cast<float4*>(op) = v0;
    *reinterpret_cast<float4*>(op + 4) = v1;
    if (lg == 0) out[B_TOTAL * D + blockIdx.x * SPB + lr] = lp;
  }
}

extern "C" void kernel_launch(void* const* d_in, const int* in_sizes, int n_in,
                              void* d_out, int out_size, void* d_ws, size_t ws_size,
                              hipStream_t stream) {
  const float* x    = (const float*)d_in[0];
  const float* logp = (const float*)d_in[1];
  const float* w1   = (const float*)d_in[2];
  const float* b1   = (const float*)d_in[3];
  const float* w2   = (const float*)d_in[4];
  // d_in[5] (b2) shifts u only; it does not affect grad_u or the laplacian.
  float* out = (float*)d_out;

  ma_flow_kernel<<<B_TOTAL / SPB, 256, 0, stream>>>(x, logp, w1, b1, w2, out);
}

// Round 6
// 21.288 us; speedup vs baseline: 1.2766x; 1.2766x over previous
//
#include <hip/hip_runtime.h>

#define B_TOTAL 4096
#define D 32
#define H 256
#define SPB 16           // samples per block (= MFMA M, fully used)
#define NW 8             // waves per block
#define HPW 32           // hidden units per wave (8 waves x 32 = 256)

static constexpr float EPS = 0.1f;

typedef __attribute__((ext_vector_type(8))) short short8v;   // 8 x bf16
typedef __attribute__((ext_vector_type(4))) float f32x4;

// RNE split (preamble only — accuracy matters, cost amortized)
__device__ __forceinline__ unsigned short bf16rne(float f) {
  unsigned u = __float_as_uint(f);
  u += 0x7FFFu + ((u >> 16) & 1u);
  return (unsigned short)(u >> 16);
}
__device__ __forceinline__ float fromb(unsigned short h) {
  return __uint_as_float(((unsigned)h) << 16);
}
__device__ __forceinline__ void split_rne(float f, unsigned short& hi, unsigned short& lo) {
  hi = bf16rne(f); lo = bf16rne(f - fromb(hi));
}

#define MFMA16(A, Bf, C) __builtin_amdgcn_mfma_f32_16x16x32_bf16((A), (Bf), (C), 0, 0, 0)

__global__ __launch_bounds__(512, 2) void ma_flow_kernel(
    const float* __restrict__ x_in, const float* __restrict__ logp_in,
    const float* __restrict__ w1, const float* __restrict__ b1,
    const float* __restrict__ w2, float* __restrict__ out)
{
  // per-wave a-transpose buffer: packed (lo16<<16)|hi16 per h. row stride 36 dw
  __shared__ __align__(16) unsigned aBuf[NW][SPB][36];
  // per-wave partial g (+lap in col 32), double-buffered by stage parity
  __shared__ __align__(16) float partG[2][NW][SPB][36];

  const int tid = threadIdx.x;
  const int l  = tid & 63;
  const int wv = tid >> 6;       // wave id = 32-h slice (0..7)
  const int lr = l & 15;         // MFMA m/n lane index; owned sample
  const int lg = l >> 4;         // MFMA k-group; owned dim-octet
  const int hbase = wv * HPW;

  // ---------------- weight fragments (registers, hi/lo bf16 split) -------------
  // z-pass: B[k=d][n=h]. lane: k = lg*8+j, n = tau*16+lr ; tau in {0,1}
  short8v Bzh[2], Bzl[2];
  float b1v[2], w2v[2], w2cv[2];
#pragma unroll
  for (int tau = 0; tau < 2; ++tau) {
    const int h = hbase + tau * 16 + lr;
    float cpart = 0.0f;
    short8v hi, lo;
#pragma unroll
    for (int j = 0; j < 8; ++j) {
      float w = w1[(lg * 8 + j) * H + h];
      cpart = fmaf(w, w, cpart);
      unsigned short hb, lb; split_rne(w, hb, lb);
      hi[j] = (short)hb; lo[j] = (short)lb;
    }
    Bzh[tau] = hi; Bzl[tau] = lo;
    cpart += __shfl_xor(cpart, 16);            // sum the 4 k-groups -> c_h
    cpart += __shfl_xor(cpart, 32);
    b1v[tau] = b1[h];
    float w2x = w2[h];
    w2v[tau] = w2x;
    w2cv[tau] = w2x * cpart;                   // w2[h] * sum_d w1[d,h]^2
  }
  // g-pass: B[k=h_local][n=d] (w1^T). lane: k = lg*8+j (single 32-k step!)
  short8v Bgh[2], Bgl[2];
#pragma unroll
  for (int nu = 0; nu < 2; ++nu) {
    const int d = nu * 16 + lr;
    const float* pp = w1 + d * H + hbase + lg * 8;
    float4 v0 = *reinterpret_cast<const float4*>(pp);
    float4 v1 = *reinterpret_cast<const float4*>(pp + 4);
    float wv8[8] = {v0.x, v0.y, v0.z, v0.w, v1.x, v1.y, v1.z, v1.w};
    short8v hi, lo;
#pragma unroll
    for (int j = 0; j < 8; ++j) {
      unsigned short hb, lb; split_rne(wv8[j], hb, lb);
      hi[j] = (short)hb; lo[j] = (short)lb;
    }
    Bgh[nu] = hi; Bgl[nu] = lo;
  }

  // ---------------- register-resident state (replicated across waves) ----------
  // lane (lr,lg) owns sample lr, dims lg*8..lg*8+7
  float x0r[8], accr[8], xcr[8];
  {
    const float* xp = x_in + (blockIdx.x * SPB + lr) * D + lg * 8;
    float4 v0 = *reinterpret_cast<const float4*>(xp);
    float4 v1 = *reinterpret_cast<const float4*>(xp + 4);
    x0r[0] = v0.x; x0r[1] = v0.y; x0r[2] = v0.z; x0r[3] = v0.w;
    x0r[4] = v1.x; x0r[5] = v1.y; x0r[6] = v1.z; x0r[7] = v1.w;
#pragma unroll
    for (int j = 0; j < 8; ++j) { xcr[j] = x0r[j]; accr[j] = 0.0f; }
  }
  float lp = logp_in[blockIdx.x * SPB + lr];

  // ---------------- 8 RK4 stage evaluations, ONE barrier each ------------------
  int p = 0;
#pragma unroll 1
  for (int stage = 0; stage < 8; ++stage) {
    const int st = stage & 3;
    const float wa = (st == 0 || st == 3) ? (EPS / 6.0f) : (EPS / 3.0f);
    const float wc = (st == 2) ? EPS : (EPS * 0.5f);

    // -- phase 1: xc regs -> A-frags (Dekker trunc split), z-MFMAs, sigmoid ----
    short8v ahi, alo;
#pragma unroll
    for (int j = 0; j < 8; ++j) {
      unsigned u = __float_as_uint(xcr[j]);
      float fh = __uint_as_float(u & 0xFFFF0000u);
      ahi[j] = (short)(u >> 16);
      alo[j] = (short)(__float_as_uint(xcr[j] - fh) >> 16);
    }

    float lapp[4] = {0.0f, 0.0f, 0.0f, 0.0f};
#pragma unroll
    for (int tau = 0; tau < 2; ++tau) {
      f32x4 z = {b1v[tau], b1v[tau], b1v[tau], b1v[tau]};
      z = MFMA16(ahi, Bzh[tau], z);
      z = MFMA16(alo, Bzh[tau], z);
      z = MFMA16(ahi, Bzl[tau], z);
#pragma unroll
      for (int r = 0; r < 4; ++r) {
        float E = __expf(-z[r]);
        float t = __builtin_amdgcn_rcpf(1.0f + E);           // sigmoid
        float a = t * w2v[tau];                               // s * w2
        lapp[r] = fmaf(t * t * E, w2cv[tau], lapp[r]);        // s(1-s) * w2*c
        // Dekker trunc split of a, packed (lo16<<16)|hi16
        unsigned ua = __float_as_uint(a);
        float fh = __uint_as_float(ua & 0xFFFF0000u);
        unsigned ul = __float_as_uint(a - fh);
        aBuf[wv][lg * 4 + r][tau * 16 + lr] = (ul & 0xFFFF0000u) | (ua >> 16);
      }
    }
    // wave-local fence: aBuf write->read within this wave
    asm volatile("s_waitcnt lgkmcnt(0)" ::: "memory");
    __builtin_amdgcn_sched_barrier(0);

    // -- phase 2: aBuf -> A-frags (hi+lo), g-MFMAs (one 32-k step), partG ------
    const unsigned* ap = &aBuf[wv][lr][lg * 8];
    uint4 q0 = *reinterpret_cast<const uint4*>(ap);
    uint4 q1 = *reinterpret_cast<const uint4*>(ap + 4);
    unsigned uu[8] = {q0.x, q0.y, q0.z, q0.w, q1.x, q1.y, q1.z, q1.w};
    short8v aH, aL;
#pragma unroll
    for (int j = 0; j < 8; ++j) {
      aH[j] = (short)(uu[j] & 0xFFFFu);
      aL[j] = (short)(uu[j] >> 16);
    }
#pragma unroll
    for (int nu = 0; nu < 2; ++nu) {
      f32x4 g = {0.0f, 0.0f, 0.0f, 0.0f};
      g = MFMA16(aH, Bgh[nu], g);
      g = MFMA16(aL, Bgh[nu], g);
      g = MFMA16(aH, Bgl[nu], g);
#pragma unroll
      for (int r = 0; r < 4; ++r)
        partG[p][wv][lg * 4 + r][nu * 16 + lr] = g[r];
    }
    // laplacian: reduce over the wave's 16 h-columns, deposit in col 32
#pragma unroll
    for (int m = 1; m < 16; m <<= 1)
#pragma unroll
      for (int r = 0; r < 4; ++r) lapp[r] += __shfl_xor(lapp[r], m);
    if (lr == 0) {
#pragma unroll
      for (int r = 0; r < 4; ++r) partG[p][wv][lg * 4 + r][32] = lapp[r];
    }
    __syncthreads();   // the stage's single barrier

    // -- phase 3: cross-wave reduce straight into register state ---------------
    f32x4 ga = {0.0f, 0.0f, 0.0f, 0.0f}, gb = {0.0f, 0.0f, 0.0f, 0.0f};
    float lapt = 0.0f;
#pragma unroll
    for (int w = 0; w < NW; ++w) {
      const float* q = &partG[p][w][lr][lg * 8];
      ga += *reinterpret_cast<const f32x4*>(q);
      gb += *reinterpret_cast<const f32x4*>(q + 4);
      lapt += partG[p][w][lr][32];
    }
    float gv[8] = {ga.x, ga.y, ga.z, ga.w, gb.x, gb.y, gb.z, gb.w};
    lp = fmaf(-wa, lapt, lp);
#pragma unroll
    for (int j = 0; j < 8; ++j) {
      accr[j] = fmaf(wa, gv[j], accr[j]);
      if (st < 3) {
        xcr[j] = fmaf(wc, gv[j], x0r[j]);
      } else {
        x0r[j] += accr[j];
        xcr[j] = x0r[j];
        accr[j] = 0.0f;
      }
    }
    p ^= 1;            // partG double-buffer: WAR covered by next stage's barrier
  }

  // ---------------- output (state replicated: wave 0 only stores) --------------
  if (wv == 0) {
    float* op = out + (blockIdx.x * SPB + lr) * D + lg * 8;
    float4 v0, v1;
    v0.x = x0r[0]; v0.y = x0r[1]; v0.z = x0r[2]; v0.w = x0r[3];
    v1.x = x0r[4]; v1.y = x0r[5]; v1.z = x0r[6]; v1.w = x0r[7];
    *reinterpret_cast<float4*>(op) = v0;
    *reinterpret_cast<float4*>(op + 4) = v1;
    if (lg == 0) out[B_TOTAL * D + blockIdx.x * SPB + lr] = lp;
  }
}

extern "C" void kernel_launch(void* const* d_in, const int* in_sizes, int n_in,
                              void* d_out, int out_size, void* d_ws, size_t ws_size,
                              hipStream_t stream) {
  const float* x    = (const float*)d_in[0];
  const float* logp = (const float*)d_in[1];
  const float* w1   = (const float*)d_in[2];
  const float* b1   = (const float*)d_in[3];
  const float* w2   = (const float*)d_in[4];
  // d_in[5] (b2) shifts u only; it does not affect grad_u or the laplacian.
  float* out = (float*)d_out;

  ma_flow_kernel<<<B_TOTAL / SPB, 512, 0, stream>>>(x, logp, w1, b1, w2, out);
}

// Round 7
// 16.254 us; speedup vs baseline: 1.6720x; 1.3097x over previous
//
#include <hip/hip_runtime.h>

#define B_TOTAL 4096
#define D 32
#define H 256
#define SPB 16           // samples per block (= MFMA M)
#define NW 8             // waves per block
#define HPW 32           // hidden units per wave

static constexpr float EPS = 0.1f;

typedef __attribute__((ext_vector_type(8))) short short8v;   // 8 x bf16
typedef __attribute__((ext_vector_type(4))) float f32x4;

__device__ __forceinline__ unsigned short bf16rne(float f) {
  unsigned u = __float_as_uint(f);
  u += 0x7FFFu + ((u >> 16) & 1u);
  return (unsigned short)(u >> 16);
}
__device__ __forceinline__ float fromb(unsigned short h) {
  return __uint_as_float(((unsigned)h) << 16);
}
__device__ __forceinline__ void split_rne(float f, unsigned short& hi, unsigned short& lo) {
  hi = bf16rne(f); lo = bf16rne(f - fromb(hi));
}

#define MFMA16(A, Bf, C) __builtin_amdgcn_mfma_f32_16x16x32_bf16((A), (Bf), (C), 0, 0, 0)

__global__ __launch_bounds__(512, 2) void ma_flow_kernel(
    const float* __restrict__ x_in, const float* __restrict__ logp_in,
    const float* __restrict__ w1, const float* __restrict__ b1,
    const float* __restrict__ w2, float* __restrict__ out)
{
  __shared__ __align__(16) unsigned aBuf[NW][SPB][36];  // per-wave a-transpose (packed hi/lo bf16)
  __shared__ __align__(16) float partG[NW][SPB][36];    // per-wave partial g
  __shared__ __align__(16) float xcL[SPB][36];          // stage input (shared by all waves)

  const int tid = threadIdx.x;
  const int l  = tid & 63;
  const int wv = tid >> 6;       // wave id = 32-h slice
  const int lr = l & 15;         // MFMA m/n lane index
  const int lg = l >> 4;         // MFMA k-group
  const int hbase = wv * HPW;
  const int s_own = tid >> 5;    // owned sample  (phase-3 mapping)
  const int d_own = tid & 31;    // owned dim

  // ---------------- weight fragments (registers, hi/lo bf16 split) -------------
  short8v Bzh[2], Bzl[2];
  float b1v[2], w2v[2], w2cv[2];
#pragma unroll
  for (int tau = 0; tau < 2; ++tau) {
    const int h = hbase + tau * 16 + lr;
    float cpart = 0.0f;
    short8v hi, lo;
#pragma unroll
    for (int j = 0; j < 8; ++j) {
      float w = w1[(lg * 8 + j) * H + h];
      cpart = fmaf(w, w, cpart);
      unsigned short hb, lb; split_rne(w, hb, lb);
      hi[j] = (short)hb; lo[j] = (short)lb;
    }
    Bzh[tau] = hi; Bzl[tau] = lo;
    cpart += __shfl_xor(cpart, 16);            // sum the 4 k-groups -> c_h
    cpart += __shfl_xor(cpart, 32);
    b1v[tau] = b1[h];
    float w2x = w2[h];
    w2v[tau] = w2x;
    w2cv[tau] = w2x * cpart;                   // w2[h] * sum_d w1[d,h]^2
  }
  short8v Bgh[2], Bgl[2];
#pragma unroll
  for (int nu = 0; nu < 2; ++nu) {
    const int d = nu * 16 + lr;
    const float* pp = w1 + d * H + hbase + lg * 8;
    float4 v0 = *reinterpret_cast<const float4*>(pp);
    float4 v1 = *reinterpret_cast<const float4*>(pp + 4);
    float wv8[8] = {v0.x, v0.y, v0.z, v0.w, v1.x, v1.y, v1.z, v1.w};
    short8v hi, lo;
#pragma unroll
    for (int j = 0; j < 8; ++j) {
      unsigned short hb, lb; split_rne(wv8[j], hb, lb);
      hi[j] = (short)hb; lo[j] = (short)lb;
    }
    Bgh[nu] = hi; Bgl[nu] = lo;
  }

  // ---------------- state init: thread owns (s_own, d_own) ---------------------
  float x0r = x_in[blockIdx.x * (SPB * D) + tid];   // coalesced
  float accr = 0.0f;
  xcL[s_own][d_own] = x0r;
  float lp = (tid < SPB) ? logp_in[blockIdx.x * SPB + tid] : 0.0f;
  float lapAcc[4] = {0.0f, 0.0f, 0.0f, 0.0f};       // wa-weighted lap partials
  __syncthreads();

  // ---------------- 8 RK4 stage evaluations, TWO barriers each -----------------
#pragma unroll 1
  for (int stage = 0; stage < 8; ++stage) {
    const int st = stage & 3;
    const float wa = (st == 0 || st == 3) ? (EPS / 6.0f) : (EPS / 3.0f);
    const float wc = (st == 2) ? EPS : (EPS * 0.5f);

    // -- phase 1: xcL -> A-frags (Dekker split), z-MFMAs, sigmoid, aBuf --------
    const float* xrow = &xcL[lr][lg * 8];
    f32x4 xv0 = *reinterpret_cast<const f32x4*>(xrow);
    f32x4 xv1 = *reinterpret_cast<const f32x4*>(xrow + 4);
    short8v ahi, alo;
#pragma unroll
    for (int j = 0; j < 4; ++j) {
      float xa = xv0[j];
      unsigned u = __float_as_uint(xa);
      ahi[j] = (short)(u >> 16);
      alo[j] = (short)(__float_as_uint(xa - __uint_as_float(u & 0xFFFF0000u)) >> 16);
      float xb = xv1[j];
      unsigned u2 = __float_as_uint(xb);
      ahi[4 + j] = (short)(u2 >> 16);
      alo[4 + j] = (short)(__float_as_uint(xb - __uint_as_float(u2 & 0xFFFF0000u)) >> 16);
    }

    float slap[4] = {0.0f, 0.0f, 0.0f, 0.0f};
#pragma unroll
    for (int tau = 0; tau < 2; ++tau) {
      f32x4 z = {b1v[tau], b1v[tau], b1v[tau], b1v[tau]};
      z = MFMA16(ahi, Bzh[tau], z);
      z = MFMA16(alo, Bzh[tau], z);
      z = MFMA16(ahi, Bzl[tau], z);
#pragma unroll
      for (int r = 0; r < 4; ++r) {
        float E = __expf(-z[r]);
        float t = __builtin_amdgcn_rcpf(1.0f + E);     // sigmoid
        float a = t * w2v[tau];                         // s * w2
        slap[r] = fmaf(t * t * E, w2cv[tau], slap[r]);  // s(1-s) * w2*c
        unsigned ua = __float_as_uint(a);
        float fh = __uint_as_float(ua & 0xFFFF0000u);
        unsigned ul = __float_as_uint(a - fh);
        unsigned* bp = &aBuf[wv][lg * 4 + r][lr];
        bp[tau * 16] = (ul & 0xFFFF0000u) | (ua >> 16); // pairs mergeable -> ds_write2
      }
    }
#pragma unroll
    for (int r = 0; r < 4; ++r) lapAcc[r] = fmaf(wa, slap[r], lapAcc[r]);

    // wave-local fence: aBuf write->read within this wave only
    asm volatile("s_waitcnt lgkmcnt(0)" ::: "memory");
    __builtin_amdgcn_sched_barrier(0);

    // -- phase 2: aBuf -> A-frags (hi+lo), g-MFMAs, partG write ----------------
    const unsigned* ap = &aBuf[wv][lr][lg * 8];
    uint4 q0 = *reinterpret_cast<const uint4*>(ap);
    uint4 q1 = *reinterpret_cast<const uint4*>(ap + 4);
    unsigned uu[8] = {q0.x, q0.y, q0.z, q0.w, q1.x, q1.y, q1.z, q1.w};
    short8v aH, aL;
#pragma unroll
    for (int j = 0; j < 8; ++j) {
      aH[j] = (short)(uu[j] & 0xFFFFu);
      aL[j] = (short)(uu[j] >> 16);
    }
#pragma unroll
    for (int nu = 0; nu < 2; ++nu) {
      f32x4 g = {0.0f, 0.0f, 0.0f, 0.0f};
      g = MFMA16(aH, Bgh[nu], g);
      g = MFMA16(aL, Bgh[nu], g);
      g = MFMA16(aH, Bgl[nu], g);
#pragma unroll
      for (int r = 0; r < 4; ++r)
        partG[wv][lg * 4 + r][nu * 16 + lr] = g[r];
    }
    __syncthreads();                     // barrier 1: partG ready

    // -- phase 3: owner-thread reduce (NO redundancy), state update ------------
    float gsum = 0.0f;
#pragma unroll
    for (int w = 0; w < NW; ++w) gsum += partG[w][s_own][d_own];  // 8x ds_read_b32, 2-way banks
    accr = fmaf(wa, gsum, accr);
    float xw;
    if (st < 3) {
      xw = fmaf(wc, gsum, x0r);
    } else {
      x0r += accr; accr = 0.0f; xw = x0r;
    }
    xcL[s_own][d_own] = xw;
    __syncthreads();                     // barrier 2: xcL ready (also partG WAR)
  }

  // ---------------- final laplacian reduce (once) -------------------------------
#pragma unroll
  for (int m = 1; m < 16; m <<= 1)
#pragma unroll
    for (int r = 0; r < 4; ++r) lapAcc[r] += __shfl_xor(lapAcc[r], m);
  if (lr == 0) {
#pragma unroll
    for (int r = 0; r < 4; ++r) partG[wv][lg * 4 + r][0] = lapAcc[r];
  }
  __syncthreads();

  // ---------------- output -------------------------------------------------------
  out[blockIdx.x * (SPB * D) + tid] = x0r;             // coalesced
  if (tid < SPB) {
    float lt = 0.0f;
#pragma unroll
    for (int w = 0; w < NW; ++w) lt += partG[w][tid][0];
    out[B_TOTAL * D + blockIdx.x * SPB + tid] = lp - lt;
  }
}

extern "C" void kernel_launch(void* const* d_in, const int* in_sizes, int n_in,
                              void* d_out, int out_size, void* d_ws, size_t ws_size,
                              hipStream_t stream) {
  const float* x    = (const float*)d_in[0];
  const float* logp = (const float*)d_in[1];
  const float* w1   = (const float*)d_in[2];
  const float* b1   = (const float*)d_in[3];
  const float* w2   = (const float*)d_in[4];
  // d_in[5] (b2) shifts u only; it does not affect grad_u or the laplacian.
  float* out = (float*)d_out;

  ma_flow_kernel<<<B_TOTAL / SPB, 512, 0, stream>>>(x, logp, w1, b1, w2, out);
}